// Round 2
// baseline (440.072 us; speedup 1.0000x reference)
//
#include <hip/hip_runtime.h>

// Problem constants
constexpr int BB = 2;        // batch
constexpr int CM = 96;       // d_model
constexpr int CI = 192;      // d_inner
constexpr int HH = 128;
constexpr int WW = 128;
constexpr int NPIX = HH * WW;     // 16384
constexpr int DS = 16;            // d_state
constexpr int NDIRS = 4;
constexpr int DC = NDIRS * CI;    // 768

// workspace layout (floats)
constexpr size_t OFF_X1PRE = 0;                       // 6,291,456
constexpr size_t OFF_X1    = 6291456;                 // 6,291,456
constexpr size_t OFF_XP    = 12582912;                // 524,288  (b, w, h, 16)
constexpr size_t OFF_YT    = 13107200;                // 6,291,456 (b, c, w, h)
constexpr size_t OFF_GXS   = 19398656;                // 384

__device__ __forceinline__ float frcp(float x) { return __builtin_amdgcn_rcpf(x); }
__device__ __forceinline__ float sigm(float x) { return frcp(1.f + __expf(-x)); }

// ---------------------------------------------------------------------------
// K1: x1_pre = conv1x1(x, w_in)   (B,96,H,W) -> (B,192,H,W)
// grid (256, 6): x = pixel tile of 128 (b folded), y = c tile of 32
__global__ __launch_bounds__(256) void k1_conv_in(const float* __restrict__ x,
                                                  const float* __restrict__ w_in,
                                                  float* __restrict__ x1pre) {
    __shared__ float xs[16][128];
    __shared__ float wsh[16][32];
    int pt = blockIdx.x;
    int b = pt >> 7;
    int pxb = (pt & 127) * 128;
    int cb = blockIdx.y * 32;
    int tid = threadIdx.x;
    int cl0 = (tid >> 5) * 4;
    int px0 = (tid & 31) * 4;
    float acc[4][4];
#pragma unroll
    for (int i = 0; i < 4; i++)
#pragma unroll
        for (int j = 0; j < 4; j++) acc[i][j] = 0.f;

    for (int m0 = 0; m0 < 96; m0 += 16) {
        {
            int e = tid * 8;
            int ml = e >> 7, pp = e & 127;
            const float* src = &x[((size_t)(b * CM + m0 + ml)) * NPIX + pxb + pp];
            float4 v0 = *(const float4*)(src);
            float4 v1 = *(const float4*)(src + 4);
            *(float4*)&xs[ml][pp] = v0;
            *(float4*)&xs[ml][pp + 4] = v1;
        }
        if (tid < 128) {
            int cl = tid >> 2, mq = (tid & 3) * 4;
            float4 v = *(const float4*)&w_in[(size_t)(cb + cl) * CM + m0 + mq];
            wsh[mq + 0][cl] = v.x; wsh[mq + 1][cl] = v.y;
            wsh[mq + 2][cl] = v.z; wsh[mq + 3][cl] = v.w;
        }
        __syncthreads();
#pragma unroll
        for (int m = 0; m < 16; m++) {
            float4 wv = *(const float4*)&wsh[m][cl0];
            float4 xv = *(const float4*)&xs[m][px0];
            float wr[4] = {wv.x, wv.y, wv.z, wv.w};
            float xr[4] = {xv.x, xv.y, xv.z, xv.w};
#pragma unroll
            for (int i = 0; i < 4; i++)
#pragma unroll
                for (int j = 0; j < 4; j++) acc[i][j] += wr[i] * xr[j];
        }
        __syncthreads();
    }
#pragma unroll
    for (int i = 0; i < 4; i++) {
        float4 v = {acc[i][0], acc[i][1], acc[i][2], acc[i][3]};
        *(float4*)&x1pre[((size_t)(b * CI + cb + cl0 + i)) * NPIX + pxb + px0] = v;
    }
}

// ---------------------------------------------------------------------------
// K2: x1 = dwconv3x3(x1_pre) + b_dw   (SAME, groups=192)
__global__ __launch_bounds__(256) void k2_dwconv(const float* __restrict__ x1pre,
                                                 const float* __restrict__ w_dw,
                                                 const float* __restrict__ b_dw,
                                                 float* __restrict__ x1) {
    int gid = blockIdx.x * 256 + threadIdx.x;     // 0 .. 6291456-1
    int px = gid & (NPIX - 1);
    int bc = gid >> 14;
    int c = bc % CI;
    int h = px >> 7, w = px & 127;
    const float* base = x1pre + (size_t)bc * NPIX;
    float s = 0.f;
#pragma unroll
    for (int dy = -1; dy <= 1; dy++) {
        int hh = h + dy;
        if ((unsigned)hh < 128u) {
#pragma unroll
            for (int dx = -1; dx <= 1; dx++) {
                int w2 = w + dx;
                if ((unsigned)w2 < 128u)
                    s += w_dw[c * 9 + (dy + 1) * 3 + (dx + 1)] * base[hh * 128 + w2];
            }
        }
    }
    x1[gid] = s + b_dw[c];
}

// ---------------------------------------------------------------------------
// K3: xp = conv1x1(x1, w_xdown) stored TRANSPOSED as (b, w, h, 16) so the
// scan kernel's gate loads (lanes sweep h at fixed w=t) are coalesced AND
// correct: gates live in ORIGINAL image coords for all 4 directions.
// grid = B*128 (one h-row each); 256 threads = 128 w-pixels x 2 c-halves
__global__ __launch_bounds__(256) void k3_xp(const float* __restrict__ x1,
                                             const float* __restrict__ w_xdown,
                                             float* __restrict__ xp) {
    __shared__ float wsh[DS * CI];   // [s][c] linear, 12KB
    __shared__ float ph[DS][128];    // 8KB
    int blk = blockIdx.x;
    int b = blk >> 7, t = blk & 127;     // t = h-row index
    int tid = threadIdx.x;
    for (int e = tid * 4; e < DS * CI; e += 1024) {
        *(float4*)&wsh[e] = *(const float4*)&w_xdown[e];
    }
    __syncthreads();
    int i = tid & 127;                   // i = w index
    int half = tid >> 7;
    int c0 = half * 96;
    float acc[DS];
#pragma unroll
    for (int s = 0; s < DS; s++) acc[s] = 0.f;
    const float* xbase = x1 + ((size_t)b * CI + c0) * NPIX + t * 128 + i;
    for (int c = 0; c < 96; c++) {
        float v = xbase[(size_t)c * NPIX];
#pragma unroll
        for (int s = 0; s < DS; s++) acc[s] += wsh[s * CI + c0 + c] * v;
    }
    if (half == 1) {
#pragma unroll
        for (int s = 0; s < DS; s++) ph[s][i] = acc[s];
    }
    __syncthreads();
    if (half == 0) {
        float out[DS];
#pragma unroll
        for (int s = 0; s < DS; s++) out[s] = acc[s] + ph[s][i];
        // store at (b, w=i, h=t): scattered 64B/thread, only 2MB total
        float4* dst = (float4*)&xp[(((size_t)b * 128 + i) * 128 + t) * DS];
#pragma unroll
        for (int q = 0; q < 4; q++) dst[q] = *(float4*)&out[q * 4];
    }
}

// ---------------------------------------------------------------------------
// K4: fused gate-compute + 4-direction tridiagonal scan + direction merge.
// grid = B*CI blocks; 256 threads = 4 waves (wave n = direction n).
// Lane l owns rows {l, l+64}. h-neighbors via shuffles. One barrier/step.
// Gates/lambda/gain/skip are rank-16: recomputed per pixel from xp (image
// coords (h=row, w=t) for ALL directions — only the data views transform).
__global__ __launch_bounds__(256, 2) void k4_scan(
        const float* __restrict__ x1, const float* __restrict__ xp,
        const float* __restrict__ w_wup, const float* __restrict__ w_lup,
        const float* __restrict__ w_uup, const float* __restrict__ w_ddown,
        const float* __restrict__ w_m, float* __restrict__ yt) {
    __shared__ float plane[128][129];        // 66048 B, pad -> conflict-free rows+cols
    __shared__ float ycol[2][NDIRS][128];    // 4096 B
    int blk = blockIdx.x;                    // b*CI + c
    int c = blk % CI;
    int b = blk / CI;
    int tid = threadIdx.x;
    int n = tid >> 6;
    int l = tid & 63;

    // stage x1 plane
    {
        const float* src = x1 + (size_t)blk * NPIX;
        for (int e = tid * 4; e < NPIX; e += 1024) {
            float4 v = *(const float4*)&src[e];
            int i = e >> 7, t = e & 127;
            plane[i][t] = v.x; plane[i][t + 1] = v.y;
            plane[i][t + 2] = v.z; plane[i][t + 3] = v.w;
        }
    }
    // per-(direction, channel) weight rows -> registers
    int q = n * CI + c;
    float wGl[DS], wGm[DS], wGr[DS], wL[DS], wU[DS], wD[DS];
    float wm = w_m[n];
#pragma unroll
    for (int j = 0; j < DS; j++) {
        wGl[j] = w_wup[(size_t)q * DS + j];
        wGm[j] = w_wup[(size_t)(DC + q) * DS + j];
        wGr[j] = w_wup[(size_t)(2 * DC + q) * DS + j];
        wL[j]  = w_lup[(size_t)q * DS + j];
        wU[j]  = w_uup[(size_t)q * DS + j] * wm;
        wD[j]  = w_ddown[(size_t)q * DS + j] * wm;
    }
    __syncthreads();

    const float* xpb = xp + (size_t)b * 128 * 128 * DS;
    float hA = 0.f, hB = 0.f;

    auto loadxp = [&](int t, float (&dA)[DS], float (&dB)[DS]) {
        // xp layout (b, w, h, 16): gate pixel (h=l / l+64, w=t)
        const float4* pA = (const float4*)&xpb[((size_t)t * 128 + l) * DS];
        const float4* pB = (const float4*)&xpb[((size_t)t * 128 + l + 64) * DS];
#pragma unroll
        for (int qd = 0; qd < 4; qd++) {
            float4 va = pA[qd], vb = pB[qd];
            dA[qd * 4 + 0] = va.x; dA[qd * 4 + 1] = va.y;
            dA[qd * 4 + 2] = va.z; dA[qd * 4 + 3] = va.w;
            dB[qd * 4 + 0] = vb.x; dB[qd * 4 + 1] = vb.y;
            dB[qd * 4 + 2] = vb.z; dB[qd * 4 + 3] = vb.w;
        }
    };

    auto step = [&](int t, float (&xA)[DS], float (&xB)[DS]) {
        float XA, XB;
        if (n == 0)      { XA = plane[l][t];       XB = plane[l + 64][t]; }
        else if (n == 1) { XA = plane[t][l];       XB = plane[t][l + 64]; }
        else if (n == 2) { XA = plane[l][127 - t]; XB = plane[l + 64][127 - t]; }
        else             { XA = plane[127 - t][l]; XB = plane[127 - t][l + 64]; }
        float aGlA = 0.f, aGmA = 0.f, aGrA = 0.f, aLA = 0.f, aUA = 0.f, aDA = 0.f;
        float aGlB = 0.f, aGmB = 0.f, aGrB = 0.f, aLB = 0.f, aUB = 0.f, aDB = 0.f;
#pragma unroll
        for (int j = 0; j < DS; j++) {
            float xa = xA[j], xb = xB[j];
            aGlA += wGl[j] * xa; aGmA += wGm[j] * xa; aGrA += wGr[j] * xa;
            aLA  += wL[j] * xa;  aUA  += wU[j] * xa;  aDA  += wD[j] * xa;
            aGlB += wGl[j] * xb; aGmB += wGm[j] * xb; aGrB += wGr[j] * xb;
            aLB  += wL[j] * xb;  aUB  += wU[j] * xb;  aDB  += wD[j] * xb;
        }
        float glA = sigm(aGlA), gmA = sigm(aGmA), grA = sigm(aGrA);
        float glB = sigm(aGlB), gmB = sigm(aGmB), grB = sigm(aGrB);
        float ssA = (l == 0)  ? (gmA + grA) : (glA + gmA + grA);   // row 0
        float ssB = (l == 63) ? (glB + gmB) : (glB + gmB + grB);   // row 127
        float invA = frcp(fmaxf(ssA, 1e-7f));
        float invB = frcp(fmaxf(ssB, 1e-7f));
        // previous-step neighbor h
        float upA = __shfl_up(hA, 1);   upA = (l == 0) ? 0.f : upA;
        float dnB = __shfl_down(hB, 1); dnB = (l == 63) ? 0.f : dnB;
        float a63 = __shfl(hA, 63);
        float b0  = __shfl(hB, 0);
        float dnA = __shfl_down(hA, 1); dnA = (l == 63) ? b0 : dnA;
        float upB = __shfl_up(hB, 1);   upB = (l == 0) ? a63 : upB;
        hA = aLA * XA + glA * invA * upA + gmA * invA * hA + grA * invA * dnA;
        hB = aLB * XB + glB * invB * upB + gmB * invB * hB + grB * invB * dnB;
        int buf = t & 1;
        ycol[buf][n][l]      = hA * aUA + XA * aDA;   // wU/wD pre-scaled by w_m[n]
        ycol[buf][n][l + 64] = hB * aUB + XB * aDB;
        __syncthreads();
        if (tid < 128) {
            float y = ycol[buf][0][tid] + ycol[buf][1][tid]
                    + ycol[buf][2][tid] + ycol[buf][3][tid];
            yt[((size_t)blk * 128 + t) * 128 + tid] = y;
        }
    };

    float xpA[DS], xpB[DS], xqA[DS], xqB[DS];
    loadxp(0, xpA, xpB);
    for (int t = 0; t < 128; t += 2) {
        loadxp(t + 1, xqA, xqB);
        step(t, xpA, xpB);
        if (t < 126) loadxp(t + 2, xpA, xpB);
        step(t + 1, xqA, xqB);
    }
}

// ---------------------------------------------------------------------------
// K5: LayerNorm over channels (in-place on yt) + per-(b,c) sum of squares.
// grid = B*256 (64 pixels each); 256 threads = 64 px x 4 c-parts of 48
__global__ __launch_bounds__(256) void k5_ln(float* __restrict__ yt,
                                             const float* __restrict__ ln_w,
                                             const float* __restrict__ ln_b,
                                             float* __restrict__ gxs) {
    __shared__ float red[8][64];
    int blk = blockIdx.x;
    int b = blk >> 8;
    int pxb = (blk & 255) * 64;
    int tid = threadIdx.x;
    int pl = tid & 63, cp = tid >> 6;
    int c0 = cp * 48;
    float* base = yt + ((size_t)b * CI + c0) * NPIX + pxb + pl;
    float val[48];
    float sum = 0.f, ssq = 0.f;
#pragma unroll
    for (int j = 0; j < 48; j++) {
        float v = base[(size_t)j * NPIX];
        val[j] = v;
        sum += v; ssq += v * v;
    }
    red[cp][pl] = sum; red[4 + cp][pl] = ssq;
    __syncthreads();
    float s4 = red[0][pl] + red[1][pl] + red[2][pl] + red[3][pl];
    float q4 = red[4][pl] + red[5][pl] + red[6][pl] + red[7][pl];
    float mu = s4 * (1.f / 192.f);
    float var = q4 * (1.f / 192.f) - mu * mu;
    float rstd = rsqrtf(var + 1e-5f);
#pragma unroll
    for (int j = 0; j < 48; j++) {
        int c = c0 + j;
        float vn = (val[j] - mu) * rstd * ln_w[c] + ln_b[c];
        base[(size_t)j * NPIX] = vn;
        float sq = vn * vn;
#pragma unroll
        for (int m = 1; m < 64; m <<= 1) sq += __shfl_xor(sq, m);
        if (pl == 0) atomicAdd(&gxs[b * CI + c], sq);
    }
}

// ---------------------------------------------------------------------------
// K6: GRN (folded to per-channel affine) + out-proj conv1x1 (96x192) + NCHW store
// grid = 256: b(2) x i-tile(8, 16 rows) x t-tile(16, 8 cols); 256 threads
__global__ __launch_bounds__(256) void k6_out(
        const float* __restrict__ yt, const float* __restrict__ gxs,
        const float* __restrict__ grn_gamma, const float* __restrict__ grn_beta,
        const float* __restrict__ w_out, float* __restrict__ outp) {
    __shared__ float scale_s[CI];
    __shared__ float beta_s[CI];
    __shared__ float redv[1];
    __shared__ float stage[96 * 16 * 8];   // 48KB
    int blk = blockIdx.x;
    int b = blk >> 7;
    int rest = blk & 127;
    int i0 = (rest >> 4) * 16;
    int t0 = (rest & 15) * 8;
    int tid = threadIdx.x;
    // GRN prologue
    if (tid < CI) scale_s[tid] = sqrtf(gxs[b * CI + tid]);  // gx
    __syncthreads();
    if (tid < 64) {
        float p = scale_s[tid] + scale_s[tid + 64] + scale_s[tid + 128];
#pragma unroll
        for (int m = 1; m < 64; m <<= 1) p += __shfl_xor(p, m);
        if (tid == 0) redv[0] = p * (1.f / 192.f);
    }
    __syncthreads();
    float mean = redv[0];
    if (tid < CI) {
        float nx = scale_s[tid] / (mean + 1e-6f);
        scale_s[tid] = 1.f + grn_gamma[tid] * nx;
        beta_s[tid] = grn_beta[tid];
    }
    __syncthreads();

    int og = tid >> 5;
    int o0 = og * 12;
    int pg = tid & 31;
    int tt = pg >> 2;
    int ii0 = (pg & 3) * 4;
    float acc[12][4];
#pragma unroll
    for (int j = 0; j < 12; j++)
#pragma unroll
        for (int p = 0; p < 4; p++) acc[j][p] = 0.f;
    const float* ybase = yt + ((size_t)b * CI) * NPIX + (t0 + tt) * 128 + (i0 + ii0);
    for (int cc = 0; cc < CI; cc++) {
        float4 yv = *(const float4*)&ybase[(size_t)cc * NPIX];
        float sc = scale_s[cc], be = beta_s[cc];
        float y0 = yv.x * sc + be, y1 = yv.y * sc + be;
        float y2 = yv.z * sc + be, y3 = yv.w * sc + be;
#pragma unroll
        for (int j = 0; j < 12; j++) {
            float wv = w_out[(size_t)(o0 + j) * CI + cc];
            acc[j][0] += wv * y0; acc[j][1] += wv * y1;
            acc[j][2] += wv * y2; acc[j][3] += wv * y3;
        }
    }
#pragma unroll
    for (int j = 0; j < 12; j++)
#pragma unroll
        for (int p = 0; p < 4; p++)
            stage[((o0 + j) * 16 + ii0 + p) * 8 + tt] = acc[j][p];
    __syncthreads();
    for (int k = 0; k < 48; k++) {
        int L = k * 256 + tid;
        int o = L >> 7;
        int r = L & 127;
        int ii = r >> 3, t2 = r & 7;
        outp[((size_t)(b * CM + o)) * NPIX + (i0 + ii) * 128 + (t0 + t2)] = stage[L];
    }
}

// ---------------------------------------------------------------------------
extern "C" void kernel_launch(void* const* d_in, const int* in_sizes, int n_in,
                              void* d_out, int out_size, void* d_ws, size_t ws_size,
                              hipStream_t stream) {
    const float* x        = (const float*)d_in[0];
    const float* w_in     = (const float*)d_in[1];
    const float* w_dw     = (const float*)d_in[2];
    const float* b_dw     = (const float*)d_in[3];
    const float* w_xdown  = (const float*)d_in[4];
    const float* w_wup    = (const float*)d_in[5];
    const float* w_lup    = (const float*)d_in[6];
    const float* w_uup    = (const float*)d_in[7];
    const float* w_ddown  = (const float*)d_in[8];
    const float* w_m      = (const float*)d_in[9];
    const float* grn_gamma= (const float*)d_in[10];
    const float* grn_beta = (const float*)d_in[11];
    const float* ln_w     = (const float*)d_in[12];
    const float* ln_b     = (const float*)d_in[13];
    const float* w_out    = (const float*)d_in[14];
    float* ws    = (float*)d_ws;
    float* x1pre = ws + OFF_X1PRE;
    float* x1    = ws + OFF_X1;
    float* xp    = ws + OFF_XP;
    float* yt    = ws + OFF_YT;
    float* gxs   = ws + OFF_GXS;
    float* outp  = (float*)d_out;

    hipMemsetAsync(gxs, 0, BB * CI * sizeof(float), stream);
    dim3 g1(256, 6);
    k1_conv_in<<<g1, 256, 0, stream>>>(x, w_in, x1pre);
    k2_dwconv<<<24576, 256, 0, stream>>>(x1pre, w_dw, b_dw, x1);
    k3_xp<<<BB * 128, 256, 0, stream>>>(x1, w_xdown, xp);
    k4_scan<<<BB * CI, 256, 0, stream>>>(x1, xp, w_wup, w_lup, w_uup, w_ddown, w_m, yt);
    k5_ln<<<BB * 256, 256, 0, stream>>>(yt, ln_w, ln_b, gxs);
    k6_out<<<256, 256, 0, stream>>>(yt, gxs, grn_gamma, grn_beta, w_out, outp);
}